// Round 5
// baseline (405.585 us; speedup 1.0000x reference)
//
#include <hip/hip_runtime.h>
#include <hip/hip_bf16.h>

// DeepFM: B=16384, F_DENSE=13, F_SPARSE=26, E=16, V=100000, HID=[512,256]
// MLP is fully affine and only h.sum(axis=1) is used -> collapses exactly to
// h0 . w_eff + scalarC.
// R5: bucket-sorted gather to create DRAM row-buffer locality.
//   k_sort:   per sparse field, bucket rows by id into 64 buckets (LDS
//             histogram + scan); also zeroes lin[].
//   k_gather: one WG per (field,bucket); gathers emb1/emb2 lines whose
//             addresses fall in a ~100 KB slice (row-hit friendly);
//             scalar part -> atomicAdd lin[row]; sec[16] -> dense scratch.
//   k_final:  per-row: dense fields + s1 assembly + square + output.

#define B_     16384
#define FD_    13
#define FS_    26
#define F_     39
#define E_     16
#define V_     100000
#define H1_    512
#define H2_    256
#define DIN_   624
#define NBKT   64
#define INV_   0.9999950000374998f   // float(1/sqrt(1+1e-5))

typedef unsigned int uint_t;

// ---------------- precompute kernels ----------------

__global__ void k_v2(const float* __restrict__ Lw2, const float* __restrict__ g2,
                     float* __restrict__ v2) {
    int i = blockIdx.x;
    int l = threadIdx.x;
    float acc = 0.f;
#pragma unroll
    for (int t = 0; t < 4; ++t) {
        int j = t * 64 + l;
        acc += Lw2[i * H2_ + j] * g2[j];
    }
#pragma unroll
    for (int off = 32; off >= 1; off >>= 1)
        acc += __shfl_xor(acc, off, 64);
    if (l == 0) v2[i] = acc * INV_;
}

__global__ void k_weff(const float* __restrict__ Lw1, const float* __restrict__ g1,
                       const float* __restrict__ v2, float* __restrict__ w_eff) {
    __shared__ float red[4];
    int k = blockIdx.x;
    int t = threadIdx.x;
    float acc = Lw1[k * H1_ + t]       * g1[t]       * v2[t]
              + Lw1[k * H1_ + t + 256] * g1[t + 256] * v2[t + 256];
#pragma unroll
    for (int off = 32; off >= 1; off >>= 1)
        acc += __shfl_xor(acc, off, 64);
    if ((t & 63) == 0) red[t >> 6] = acc;
    __syncthreads();
    if (t == 0)
        w_eff[k] = (red[0] + red[1] + red[2] + red[3]) * INV_;
}

__global__ void k_scalar(const float* __restrict__ Lb1, const float* __restrict__ g1,
                         const float* __restrict__ be1, const float* __restrict__ v2,
                         const float* __restrict__ Lb2, const float* __restrict__ g2,
                         const float* __restrict__ be2, float* __restrict__ scalarC) {
    __shared__ float red[8];
    int t = threadIdx.x;
    float val = (Lb1[t] * INV_ * g1[t] + be1[t]) * v2[t];
    if (t < H2_)
        val += Lb2[t] * INV_ * g2[t] + be2[t];
#pragma unroll
    for (int off = 32; off >= 1; off >>= 1)
        val += __shfl_xor(val, off, 64);
    if ((t & 63) == 0) red[t >> 6] = val;
    __syncthreads();
    if (t == 0) {
        float s = 0.f;
#pragma unroll
        for (int w = 0; w < 8; ++w) s += red[w];
        scalarC[0] = s;
    }
}

// ---------------- phase 0: per-field bucket sort (+ zero lin) -------------
// Grid: 26 blocks x 256 threads. Block f sorts field f's rows by id bucket.
__global__ __launch_bounds__(256) void k_sort(const int* __restrict__ Xi,
                                              uint_t* __restrict__ sorted,
                                              uint_t* __restrict__ bstart,
                                              float*  __restrict__ lin) {
    __shared__ uint_t cnt[NBKT];
    __shared__ uint_t off[NBKT + 1];
    __shared__ uint_t cur[NBKT];
    const int f   = blockIdx.x;
    const int tid = threadIdx.x;

    // zero lin[] cooperatively (26*256 = 6656 threads)
    for (int i = blockIdx.x * 256 + tid; i < B_; i += 26 * 256)
        lin[i] = 0.f;

    if (tid < NBKT) cnt[tid] = 0;
    __syncthreads();
    for (int row = tid; row < B_; row += 256) {
        uint_t id = (uint_t)Xi[row * F_ + FD_ + f];
        atomicAdd(&cnt[(id * (uint_t)NBKT) / (uint_t)V_], 1u);
    }
    __syncthreads();
    if (tid == 0) {
        uint_t a = 0;
        for (int b = 0; b < NBKT; ++b) { off[b] = a; a += cnt[b]; }
        off[NBKT] = a;   // == B_
    }
    __syncthreads();
    if (tid < NBKT) cur[tid] = off[tid];
    if (tid < NBKT + 1) bstart[f * (NBKT + 1) + tid] = off[tid];
    __syncthreads();
    for (int row = tid; row < B_; row += 256) {
        uint_t id = (uint_t)Xi[row * F_ + FD_ + f];
        uint_t b  = (id * (uint_t)NBKT) / (uint_t)V_;
        uint_t pos = atomicAdd(&cur[b], 1u);
        sorted[f * B_ + pos] = ((uint_t)row << 17) | id;   // id < 2^17
    }
}

// ---------------- phase B: bucketed gather ----------------
// Grid: 26*64 blocks x 256 threads. Block = (field, bucket).
// 64 entry-slots x 4 lanes; lane r handles e-quad r (float4).
__global__ __launch_bounds__(256) void k_gather(
        const float* __restrict__ Xv,
        const float* __restrict__ emb1, const float* __restrict__ emb2,
        const float* __restrict__ w_eff,
        const uint_t* __restrict__ sorted, const uint_t* __restrict__ bstart,
        float* __restrict__ lin, float* __restrict__ scratch) {
    const int f = blockIdx.x >> 6;
    const int b = blockIdx.x & (NBKT - 1);
    const uint_t start = bstart[f * (NBKT + 1) + b];
    const uint_t end   = bstart[f * (NBKT + 1) + b + 1];
    const int r    = threadIdx.x & 3;
    const int slot = threadIdx.x >> 2;

    const float4* e1t = (const float4*)emb1;
    const float4* e2t = (const float4*)emb2;
    const float4  wq  = ((const float4*)w_eff)[(FD_ + f) * 4 + r];
    float4* scr4 = (float4*)scratch;

    for (uint_t i = start + slot; i < end; i += 64) {
        uint_t packed = sorted[f * B_ + i];
        int row = (int)(packed >> 17);
        int id  = (int)(packed & 0x1FFFFu);
        float xv = Xv[row * F_ + FD_ + f];
        size_t o = (size_t)(f * V_ + id) * 4 + r;
        float4 e1 = e1t[o];
        float4 e2 = e2t[o];
        float4 sec;
        sec.x = e2.x * xv; sec.y = e2.y * xv; sec.z = e2.z * xv; sec.w = e2.w * xv;
        float p = e1.x * xv + sec.x * wq.x - 0.5f * sec.x * sec.x
                + e1.y * xv + sec.y * wq.y - 0.5f * sec.y * sec.y
                + e1.z * xv + sec.z * wq.z - 0.5f * sec.z * sec.z
                + e1.w * xv + sec.w * wq.w - 0.5f * sec.w * sec.w;
        p += __shfl_xor(p, 1, 4);
        p += __shfl_xor(p, 2, 4);
        if (r == 0) atomicAdd(&lin[row], p);
        scr4[(size_t)(f * B_ + row) * 4 + r] = sec;
    }
}

// ---------------- phase C: per-row finale ----------------
// Grid: 64 blocks x 256 threads; thread = row.
__global__ __launch_bounds__(256) void k_final(
        const int* __restrict__ Xi, const float* __restrict__ Xv,
        const float* __restrict__ W1, const float* __restrict__ b1,
        const float* __restrict__ W2, const float* __restrict__ b2,
        const float* __restrict__ w_eff, const float* __restrict__ scalarC,
        const float* __restrict__ lin, const float* __restrict__ scratch,
        const float* __restrict__ bias, float* __restrict__ out) {
    __shared__ __align__(16) float sTab[832 + 208];  // W1|b1|W2|b2 | w_eff dense part
    const int tid = threadIdx.x;
    for (int i = tid; i < 208; i += 256) {
        sTab[i]       = W1[i];
        sTab[208 + i] = b1[i];
        sTab[416 + i] = W2[i];
        sTab[624 + i] = b2[i];
        sTab[832 + i] = w_eff[i];   // first 208 = dense fields
    }
    __syncthreads();

    const int row = blockIdx.x * 256 + tid;
    const float4* st4  = (const float4*)sTab;  // [0,52) W1 |52 b1 |104 W2 |156 b2 |208,260) weff
    const float4* scr4 = (const float4*)scratch;

    float4 s1q[4];
#pragma unroll
    for (int q = 0; q < 4; ++q) { s1q[q].x = 0.f; s1q[q].y = 0.f; s1q[q].z = 0.f; s1q[q].w = 0.f; }
    float acc = lin[row];

#pragma unroll
    for (int f = 0; f < FD_; ++f) {
        float xi = (float)Xi[row * F_ + f];
        float xv = Xv[row * F_ + f];
#pragma unroll
        for (int q = 0; q < 4; ++q) {
            float4 w1  = st4[f * 4 + q];
            float4 bb1 = st4[52 + f * 4 + q];
            float4 w2  = st4[104 + f * 4 + q];
            float4 bb2 = st4[156 + f * 4 + q];
            float4 wq  = st4[208 + f * 4 + q];
            float4 sec;
            sec.x = xi * w2.x + bb2.x; sec.y = xi * w2.y + bb2.y;
            sec.z = xi * w2.z + bb2.z; sec.w = xi * w2.w + bb2.w;
            acc += (xi * w1.x + bb1.x) * xv + (xi * w1.y + bb1.y) * xv
                 + (xi * w1.z + bb1.z) * xv + (xi * w1.w + bb1.w) * xv;
            acc += sec.x * wq.x + sec.y * wq.y + sec.z * wq.z + sec.w * wq.w;
            acc -= 0.5f * (sec.x * sec.x + sec.y * sec.y + sec.z * sec.z + sec.w * sec.w);
            s1q[q].x += sec.x; s1q[q].y += sec.y; s1q[q].z += sec.z; s1q[q].w += sec.w;
        }
    }

#pragma unroll
    for (int f = 0; f < FS_; ++f) {
#pragma unroll
        for (int q = 0; q < 4; ++q) {
            float4 s = scr4[(size_t)(f * B_ + row) * 4 + q];
            s1q[q].x += s.x; s1q[q].y += s.y; s1q[q].z += s.z; s1q[q].w += s.w;
        }
    }

    float s1sq = 0.f;
#pragma unroll
    for (int q = 0; q < 4; ++q)
        s1sq += s1q[q].x * s1q[q].x + s1q[q].y * s1q[q].y
              + s1q[q].z * s1q[q].z + s1q[q].w * s1q[q].w;

    out[row] = acc + 0.5f * s1sq + bias[row] + scalarC[0];
}

extern "C" void kernel_launch(void* const* d_in, const int* in_sizes, int n_in,
                              void* d_out, int out_size, void* d_ws, size_t ws_size,
                              hipStream_t stream) {
    const int*   Xi   = (const int*)  d_in[0];
    const float* Xv   = (const float*)d_in[1];
    const float* W1   = (const float*)d_in[2];
    const float* b1   = (const float*)d_in[3];
    const float* emb1 = (const float*)d_in[4];
    const float* W2   = (const float*)d_in[5];
    const float* b2   = (const float*)d_in[6];
    const float* emb2 = (const float*)d_in[7];
    const float* Lw1  = (const float*)d_in[8];
    const float* Lb1  = (const float*)d_in[9];
    const float* g1   = (const float*)d_in[10];
    const float* be1  = (const float*)d_in[11];
    const float* Lw2  = (const float*)d_in[12];
    const float* Lb2  = (const float*)d_in[13];
    const float* g2   = (const float*)d_in[14];
    const float* be2  = (const float*)d_in[15];
    const float* bias = (const float*)d_in[16];
    float* out = (float*)d_out;

    // ws layout (float units, 16B-aligned sections)
    float*  ws      = (float*)d_ws;
    float*  v2      = ws;                    // 512
    float*  w_eff   = ws + 512;              // 624
    float*  scalarC = ws + 1136;             // 1 (pad to 1152)
    float*  lin     = ws + 1152;             // 16384
    uint_t* bstart  = (uint_t*)(ws + 17536); // 26*65 = 1690 (pad to 1696)
    uint_t* sorted  = (uint_t*)(ws + 19232); // 26*16384 = 425984
    float*  scratch = ws + 19232 + 425984;   // 26*16384*16 floats = 27.3 MB

    k_v2    <<<H1_,  64, 0, stream>>>(Lw2, g2, v2);
    k_weff  <<<DIN_, 256, 0, stream>>>(Lw1, g1, v2, w_eff);
    k_scalar<<<1,    512, 0, stream>>>(Lb1, g1, be1, v2, Lb2, g2, be2, scalarC);
    k_sort  <<<FS_,  256, 0, stream>>>(Xi, sorted, bstart, lin);
    k_gather<<<FS_ * NBKT, 256, 0, stream>>>(Xv, emb1, emb2, w_eff, sorted,
                                             bstart, lin, scratch);
    k_final <<<B_ / 256, 256, 0, stream>>>(Xi, Xv, W1, b1, W2, b2, w_eff,
                                           scalarC, lin, scratch, bias, out);
}